// Round 1
// baseline (359.562 us; speedup 1.0000x reference)
//
#include <hip/hip_runtime.h>
#include <math.h>

#define BS 32
#define S  2048
#define H  1024

// native clang vector type — required for __builtin_nontemporal_load
typedef float vfloat4 __attribute__((ext_vector_type(4)));

// ---------------------------------------------------------------------------
// Kernel 1: v[b,h] = sum_k hidden[b,k] * W[k,h]   (v = hidden @ W)
// grid (H/256, BS) = (4,32) = 128 blocks, block 256 = 4 waves.
// Each lane owns 4 consecutive h (float4 W loads: 1 KiB/wave/instr, was 256B
// scalar). Wave w accumulates k in [w*256, w*256+256); LDS combine.
// 4 independent FMA chains per lane (vs 1 before).
// ---------------------------------------------------------------------------
__global__ __launch_bounds__(256) void compute_v(const float* __restrict__ hidden,
                                                 const float* __restrict__ W,
                                                 float* __restrict__ v) {
    __shared__ float hid[H];
    __shared__ float4 part[4][64];
    const int b    = blockIdx.y;
    const int tid  = threadIdx.x;
    const int wave = tid >> 6;
    const int lane = tid & 63;

    // stage hidden[b,:] : 256 threads x float4 = 1024 floats
    ((float4*)hid)[tid] = ((const float4*)(hidden + b * H))[tid];
    __syncthreads();

    const int h0 = blockIdx.x * 256;            // this block's 256 columns
    const float4* Wp = (const float4*)(W + (size_t)(wave * 256) * H + h0) + lane;
    const float*  hp = hid + wave * 256;

    float4 acc = {0.f, 0.f, 0.f, 0.f};
#pragma unroll 8
    for (int k = 0; k < 256; ++k) {
        float4 w4 = Wp[(size_t)k * (H / 4)];
        float  hk = hp[k];
        acc.x = fmaf(w4.x, hk, acc.x);
        acc.y = fmaf(w4.y, hk, acc.y);
        acc.z = fmaf(w4.z, hk, acc.z);
        acc.w = fmaf(w4.w, hk, acc.w);
    }

    part[wave][lane] = acc;
    __syncthreads();
    if (wave == 0) {
        float4 p0 = part[0][lane], p1 = part[1][lane];
        float4 p2 = part[2][lane], p3 = part[3][lane];
        float4 r;
        r.x = (p0.x + p1.x) + (p2.x + p3.x);
        r.y = (p0.y + p1.y) + (p2.y + p3.y);
        r.z = (p0.z + p1.z) + (p2.z + p3.z);
        r.w = (p0.w + p1.w) + (p2.w + p3.w);
        ((float4*)(v + b * H + h0))[lane] = r;
    }
}

// ---------------------------------------------------------------------------
// Kernel 2: scores[b,s] = dot(enc[b,s,:], v[b,:])
// grid (S/32, BS) = 2048 blocks (8 blocks/CU -> 32 waves/CU, full occupancy;
// was 1024 blocks / 16 waves/CU), block 256 (4 waves), 8 rows/wave in two
// pipelined groups of 4. enc loads perfectly coalesced float4, nontemporal
// (streamed exactly once). v[b,:] held in 16 regs/lane.
// Bias omitted: constant per softmax row, cancels.
// ---------------------------------------------------------------------------
__global__ __launch_bounds__(256) void compute_scores(const float* __restrict__ enc,
                                                      const float* __restrict__ v,
                                                      float* __restrict__ scores) {
    const int b    = blockIdx.y;
    const int tid  = threadIdx.x;
    const int wave = tid >> 6;
    const int lane = tid & 63;

    const float4* v4 = (const float4*)(v + b * H);
    float4 vr[4];
#pragma unroll
    for (int it = 0; it < 4; ++it) vr[it] = v4[it * 64 + lane];

    const int s0 = blockIdx.x * 32 + wave * 8;
    const vfloat4* encb = (const vfloat4*)enc + (size_t)b * S * (H / 4);

#pragma unroll
    for (int i = 0; i < 8; i += 4) {
        float acc[4] = {0.f, 0.f, 0.f, 0.f};
#pragma unroll
        for (int j = 0; j < 4; ++j) {
            const vfloat4* e4 = encb + (size_t)(s0 + i + j) * (H / 4);
#pragma unroll
            for (int it = 0; it < 4; ++it) {
                vfloat4 e = __builtin_nontemporal_load(&e4[it * 64 + lane]);
                acc[j] = fmaf(e.x, vr[it].x, acc[j]);
                acc[j] = fmaf(e.y, vr[it].y, acc[j]);
                acc[j] = fmaf(e.z, vr[it].z, acc[j]);
                acc[j] = fmaf(e.w, vr[it].w, acc[j]);
            }
        }
        // four independent 64-lane butterfly reductions — chains pipeline
#pragma unroll
        for (int off = 32; off > 0; off >>= 1) {
#pragma unroll
            for (int j = 0; j < 4; ++j)
                acc[j] += __shfl_xor(acc[j], off, 64);
        }
        if (lane < 4)
            scores[b * S + s0 + i + lane] = acc[lane];  // acc[j] valid in all lanes after xor
    }
}

// ---------------------------------------------------------------------------
// Kernel 3: in-place row softmax on scores (= d_out). grid BS, block 256,
// 8 elements/thread.
// ---------------------------------------------------------------------------
__global__ __launch_bounds__(256) void softmax_rows(float* __restrict__ scores) {
    const int b    = blockIdx.x;
    const int tid  = threadIdx.x;
    const int wave = tid >> 6;
    const int lane = tid & 63;
    __shared__ float red[4];

    float x[8];
    float m = -INFINITY;
#pragma unroll
    for (int i = 0; i < 8; ++i) {
        x[i] = scores[b * S + tid + i * 256];
        m = fmaxf(m, x[i]);
    }
#pragma unroll
    for (int off = 1; off < 64; off <<= 1)
        m = fmaxf(m, __shfl_xor(m, off, 64));
    if (lane == 0) red[wave] = m;
    __syncthreads();
    m = fmaxf(fmaxf(red[0], red[1]), fmaxf(red[2], red[3]));

    float sum = 0.f;
#pragma unroll
    for (int i = 0; i < 8; ++i) {
        x[i] = __expf(x[i] - m);
        sum += x[i];
    }
#pragma unroll
    for (int off = 1; off < 64; off <<= 1)
        sum += __shfl_xor(sum, off, 64);
    __syncthreads();   // red[] reuse
    if (lane == 0) red[wave] = sum;
    __syncthreads();
    sum = (red[0] + red[1]) + (red[2] + red[3]);
    const float inv = 1.0f / sum;

#pragma unroll
    for (int i = 0; i < 8; ++i)
        scores[b * S + tid + i * 256] = x[i] * inv;
}

extern "C" void kernel_launch(void* const* d_in, const int* in_sizes, int n_in,
                              void* d_out, int out_size, void* d_ws, size_t ws_size,
                              hipStream_t stream) {
    const float* hidden = (const float*)d_in[0];   // [BS, H]
    const float* enc    = (const float*)d_in[1];   // [BS, S, H]
    const float* W      = (const float*)d_in[2];   // [H, H]
    // d_in[3] = bias: unused — cancels in the softmax.

    float* v    = (float*)d_ws;    // BS*H floats = 128 KiB scratch
    float* outp = (float*)d_out;   // BS*S floats; scores then softmax in place

    dim3 g1(H / 256, BS);
    compute_v<<<g1, 256, 0, stream>>>(hidden, W, v);

    dim3 g2(S / 32, BS);
    compute_scores<<<g2, 256, 0, stream>>>(enc, v, outp);

    softmax_rows<<<BS, 256, 0, stream>>>(outp);
}